// Round 3
// baseline (416.449 us; speedup 1.0000x reference)
//
#include <hip/hip_runtime.h>
#include <hip/hip_bf16.h>
#include <hip/hip_cooperative_groups.h>
#include <cstdint>

namespace cg = cooperative_groups;

#define N_NODES 100000
#define HIDDEN  128
#define NEDGE   524288     // E; 2E edges total
#define NT      6250       // 16-row wave-tiles per table (100000 = 16*6250)
#define PBLK    256        // blocks per table (fused grid = 512)
#define WSTRIDE (PBLK * 4) // wave-tile stride (4 waves/block)

typedef __attribute__((ext_vector_type(8))) short short8;
typedef __attribute__((ext_vector_type(4))) float f32x4;

__device__ __forceinline__ unsigned short f2b(float f) {
    unsigned u = __float_as_uint(f);
    u += 0x7FFFu + ((u >> 16) & 1u);   // RNE; inputs finite
    return (unsigned short)(u >> 16);
}
__device__ __forceinline__ float b2f(unsigned x16) {
    return __uint_as_float(x16 << 16);
}

// async 16B/lane global->LDS. lds dest wave-uniform; HW adds lane*16.
__device__ __forceinline__ void async_copy16(const float* g, float* l) {
    __builtin_amdgcn_global_load_lds(
        (const __attribute__((address_space(1))) unsigned int*)g,
        (__attribute__((address_space(3))) unsigned int*)l,
        16, 0, 0);
}

// ============================================================================
// FUSED single-dispatch kernel (cooperative). R7 theory: wall(220.9us) minus
// kernel time (<=149us by top-5 ordering; model says ~100us) => >=72us of
// per-dispatch launch/gap overhead across 15 dispatches/replay. Cut our 3
// dispatches to 1. Phases:
//   0: per-block W1-half -> LDS -> wfrag registers (replaces wp_kernel + Wp)
//   1: precompute A tables (identical structure to R2 precompute_kernel)
//      __threadfence + grid.sync  (cross-XCD visibility of A)
//   2: edge MLP (identical per-round structure to R2 edge_kernel; each of
//      512 blocks handles 2048 edges = 32 rounds of 64)
// 512 blocks x 256 thr, 64KB LDS -> exactly 2 blocks/CU co-resident.
// ============================================================================
__global__ __launch_bounds__(256, 2)
void fused_kernel(const float* __restrict__ z_src,
                  const float* __restrict__ z_dst,
                  const int* __restrict__ pos_src,
                  const int* __restrict__ pos_dst,
                  const int* __restrict__ neg_src,
                  const int* __restrict__ neg_dst,
                  const float* __restrict__ W1,
                  const float* __restrict__ b1,
                  const float* __restrict__ W2,
                  const float* __restrict__ b2,
                  unsigned short* __restrict__ Asrc,
                  unsigned short* __restrict__ Adst,
                  float* __restrict__ out)
{
    __shared__ float zbuf[4][2][2048];   // 64 KB; phase0 staging + phase1 dbuf

    const int tid = threadIdx.x;
    const int wave = tid >> 6;
    const int lane = tid & 63;
    const int t = lane & 15;
    const int q = lane >> 4;
    const int b = (int)blockIdx.x;
    const int table = b & 1;             // interleave tables across XCDs
    const int bx = b >> 1;               // 0..255 within table

    const float* __restrict__ z = table ? z_dst : z_src;
    unsigned short* __restrict__ A = table ? Adst : Asrc;

    // ---- phase 0: stage W1 half (128x128 f32 = 64KB) linearly into LDS,
    // then each lane packs its 32 MFMA A-fragments (exactly wp_kernel's map).
    float* lin = &zbuf[0][0][0];         // 16384 floats
    {
        const float* Wh = W1 + (size_t)table * 128 * 128;
#pragma unroll
        for (int r = 0; r < 16; ++r)
            async_copy16(Wh + r * 1024 + wave * 256 + lane * 4,
                         lin + r * 1024 + wave * 256);
        __builtin_amdgcn_s_waitcnt(0xF70);  // vmcnt(0)
        __syncthreads();
    }
    short8 wfrag[32];
#pragma unroll
    for (int f = 0; f < 32; ++f) {
        const int n = f >> 2, ks = f & 3;
        short8 v;
#pragma unroll
        for (int j = 0; j < 8; ++j)
            v[j] = (short)f2b(lin[(ks * 32 + q * 8 + j) * 128 + n * 16 + t]);
        wfrag[f] = v;
    }
    __syncthreads();                     // zbuf reused by phase 1

    // b1 folded into table 0 (out col = n*16 + q*4 + r)
    float4 b1v[8];
#pragma unroll
    for (int n = 0; n < 8; ++n)
        b1v[n] = (table == 0) ? *(const float4*)(b1 + n * 16 + q * 4)
                              : make_float4(0.f, 0.f, 0.f, 0.f);

    // ---- phase 1: precompute A = bf16(z @ W1half (+b1)), R2 structure.
    const int lhi = lane >> 5;
    const int llo = lane & 31;
#define STAGE(m0, p)                                                          \
    do {                                                                      \
        _Pragma("unroll")                                                     \
        for (int j = 0; j < 8; ++j) {                                         \
            const int r = j * 2 + lhi;                                        \
            const int c = llo ^ (r & 7);                                      \
            async_copy16(z + (size_t)((m0) + r) * 128 + c * 4,                \
                         &zbuf[wave][p][j * 256]);                            \
        }                                                                     \
    } while (0)

    int tile = bx * 4 + wave;            // < 1024 < NT always
    int p = 0;
    STAGE(tile * 16, 0);
    __builtin_amdgcn_s_waitcnt(0xF70);   // vmcnt(0)
    asm volatile("" ::: "memory");

    while (tile < NT) {
        const int m0 = tile * 16;
        const int ntile = tile + WSTRIDE;
        const int nm0 = (ntile < NT ? ntile : tile) * 16;  // clamp: dummy reload
        STAGE(nm0, p ^ 1);
        asm volatile("" ::: "memory");
        __builtin_amdgcn_s_waitcnt(0xF78);  // vmcnt(8)
        asm volatile("" ::: "memory");

        short8 bb[4];
#pragma unroll
        for (int ks = 0; ks < 4; ++ks) {
            const int c0 = ks * 8 + 2 * q;
            const int s = t & 7;
            const float4 v0 = *(const float4*)&zbuf[wave][p][(t * 32 + (c0 ^ s)) * 4];
            const float4 v1 = *(const float4*)&zbuf[wave][p][(t * 32 + ((c0 + 1) ^ s)) * 4];
            bb[ks][0] = (short)f2b(v0.x); bb[ks][1] = (short)f2b(v0.y);
            bb[ks][2] = (short)f2b(v0.z); bb[ks][3] = (short)f2b(v0.w);
            bb[ks][4] = (short)f2b(v1.x); bb[ks][5] = (short)f2b(v1.y);
            bb[ks][6] = (short)f2b(v1.z); bb[ks][7] = (short)f2b(v1.w);
        }

        f32x4 acc[8];
#pragma unroll
        for (int n = 0; n < 8; ++n) acc[n] = (f32x4){0.f, 0.f, 0.f, 0.f};
#pragma unroll
        for (int n = 0; n < 8; ++n)
#pragma unroll
            for (int ks = 0; ks < 4; ++ks)
                acc[n] = __builtin_amdgcn_mfma_f32_16x16x32_bf16(
                             wfrag[n * 4 + ks], bb[ks], acc[n], 0, 0, 0);

        // epilogue: stage D through consumed LDS buffer, 16B/lane row stores
        unsigned short* ob = (unsigned short*)&zbuf[wave][p][0];
        const int sw = (t & 7) * 2;
#pragma unroll
        for (int n = 0; n < 8; ++n) {
            ushort4 h;
            h.x = f2b(acc[n][0] + b1v[n].x);
            h.y = f2b(acc[n][1] + b1v[n].y);
            h.z = f2b(acc[n][2] + b1v[n].z);
            h.w = f2b(acc[n][3] + b1v[n].w);
            *(ushort4*)&ob[t * 136 + (((n * 4 + q) ^ sw) * 4)] = h;
        }
        const int rr = lane >> 4;
#pragma unroll
        for (int it = 0; it < 4; ++it) {
            const int r = it * 4 + rr;
            const uint4 v = *(const uint4*)&ob[r * 136 + (((2 * t) ^ ((r & 7) * 2)) * 4)];
            *(uint4*)(A + (size_t)(m0 + r) * 128 + t * 8) = v;
        }
        asm volatile("" ::: "memory");

        p ^= 1;
        tile = ntile;
    }
#undef STAGE

    // ---- cross-phase: make A tables visible to all XCDs, then grid barrier
    __threadfence();
    cg::this_grid().sync();

    // ---- phase 2: edge MLP. Block b: edges [b*2048, b*2048+2048).
    const bool is_pos = b < 256;
    const int* __restrict__ sp = is_pos ? pos_src : neg_src;
    const int* __restrict__ dp = is_pos ? pos_dst : neg_dst;
    const int ebase = (b & 255) * 2048;
    const int eg = tid >> 4;             // edge group (0..15)

    float w2r[8];
#pragma unroll
    for (int j = 0; j < 8; ++j) w2r[j] = W2[t * 8 + j];
    const float bias2 = b2[0];

    const unsigned char* As = (const unsigned char*)Asrc;
    const unsigned char* Ad = (const unsigned char*)Adst;

    for (int rnd = 0; rnd < 32; ++rnd) {
        const int e0 = ebase + rnd * 64;
        unsigned soff[4], doff[4];
#pragma unroll
        for (int i = 0; i < 4; ++i) {
            soff[i] = ((unsigned)sp[e0 + i * 16 + eg] << 8) + t * 16;
            doff[i] = ((unsigned)dp[e0 + i * 16 + eg] << 8) + t * 16;
        }
        uint4 ua[4], ub[4];
#pragma unroll
        for (int i = 0; i < 4; ++i) {
            ua[i] = *(const uint4*)(As + soff[i]);
            ub[i] = *(const uint4*)(Ad + doff[i]);
        }
        asm volatile("" ::: "memory");

#define CHUNK(i, vm)                                                          \
    do {                                                                      \
        __builtin_amdgcn_s_waitcnt(0xF70 | (vm));                             \
        asm volatile("" ::: "memory");                                        \
        const unsigned* pa = (const unsigned*)&ua[i];                         \
        const unsigned* pb = (const unsigned*)&ub[i];                         \
        float acc = 0.f;                                                      \
        _Pragma("unroll")                                                     \
        for (int j2 = 0; j2 < 4; ++j2) {                                      \
            float h0 = b2f(pa[j2] & 0xFFFFu) + b2f(pb[j2] & 0xFFFFu);         \
            float h1 = b2f(pa[j2] >> 16)     + b2f(pb[j2] >> 16);             \
            h0 = fmaxf(h0, 0.f);                                              \
            h1 = fmaxf(h1, 0.f);                                              \
            acc = fmaf(h0, w2r[2 * j2], acc);                                 \
            acc = fmaf(h1, w2r[2 * j2 + 1], acc);                             \
        }                                                                     \
        acc += __shfl_xor(acc, 1);                                            \
        acc += __shfl_xor(acc, 2);                                            \
        acc += __shfl_xor(acc, 4);                                            \
        acc += __shfl_xor(acc, 8);                                            \
        if (t == 0)                                                           \
            out[(size_t)b * 2048 + rnd * 64 + (i) * 16 + eg] = acc + bias2;   \
    } while (0)

        CHUNK(0, 6);
        CHUNK(1, 4);
        CHUNK(2, 2);
        CHUNK(3, 0);
#undef CHUNK
    }
}

// ============================================================================
// Fallback path (R2's verified 3-kernel pipeline) — used if cooperative
// launch is rejected (e.g. by graph capture).
// ============================================================================
__global__ void wp_kernel(const float* __restrict__ W1,
                          unsigned short* __restrict__ Wp)
{
    const int f = blockIdx.x;
    const int tb = blockIdx.y;
    const int lane = threadIdx.x;
    const int t = lane & 15, q = lane >> 4;
    const int n = f >> 2, ks = f & 3;
    short8 v;
#pragma unroll
    for (int j = 0; j < 8; ++j)
        v[j] = (short)f2b(W1[(size_t)(tb * 128 + ks * 32 + q * 8 + j) * 128 + n * 16 + t]);
    *(short8*)(Wp + ((size_t)(tb * 32 + f) * 64 + lane) * 8) = v;
}

__global__ __launch_bounds__(256, 2)
void precompute_kernel(const float* __restrict__ z_src,
                       const float* __restrict__ z_dst,
                       const unsigned short* __restrict__ Wp,
                       const float* __restrict__ b1,
                       unsigned short* __restrict__ Asrc,
                       unsigned short* __restrict__ Adst)
{
    const int table = blockIdx.y;
    const float* __restrict__ z = table ? z_dst : z_src;
    unsigned short* __restrict__ A = table ? Adst : Asrc;

    __shared__ float zbuf[4][2][2048];

    const int tid = threadIdx.x;
    const int wave = tid >> 6;
    const int lane = tid & 63;
    const int t = lane & 15;
    const int q = lane >> 4;

    short8 wfrag[32];
    {
        const unsigned short* wp = Wp + ((size_t)table * 32 * 64 + lane) * 8;
#pragma unroll
        for (int f = 0; f < 32; ++f)
            wfrag[f] = *(const short8*)(wp + (size_t)f * 64 * 8);
    }

    float4 b1v[8];
#pragma unroll
    for (int n = 0; n < 8; ++n)
        b1v[n] = (table == 0) ? *(const float4*)(b1 + n * 16 + q * 4)
                              : make_float4(0.f, 0.f, 0.f, 0.f);

    const int lhi = lane >> 5;
    const int llo = lane & 31;
#define STAGE(m0, p)                                                          \
    do {                                                                      \
        _Pragma("unroll")                                                     \
        for (int j = 0; j < 8; ++j) {                                         \
            const int r = j * 2 + lhi;                                        \
            const int c = llo ^ (r & 7);                                      \
            async_copy16(z + (size_t)((m0) + r) * 128 + c * 4,                \
                         &zbuf[wave][p][j * 256]);                            \
        }                                                                     \
    } while (0)

    int tile = blockIdx.x * 4 + wave;
    int p = 0;
    STAGE(tile * 16, 0);
    __builtin_amdgcn_s_waitcnt(0xF70);
    asm volatile("" ::: "memory");

    while (tile < NT) {
        const int m0 = tile * 16;
        const int ntile = tile + WSTRIDE;
        const int nm0 = (ntile < NT ? ntile : tile) * 16;
        STAGE(nm0, p ^ 1);
        asm volatile("" ::: "memory");
        __builtin_amdgcn_s_waitcnt(0xF78);
        asm volatile("" ::: "memory");

        short8 bb[4];
#pragma unroll
        for (int ks = 0; ks < 4; ++ks) {
            const int c0 = ks * 8 + 2 * q;
            const int s = t & 7;
            const float4 v0 = *(const float4*)&zbuf[wave][p][(t * 32 + (c0 ^ s)) * 4];
            const float4 v1 = *(const float4*)&zbuf[wave][p][(t * 32 + ((c0 + 1) ^ s)) * 4];
            bb[ks][0] = (short)f2b(v0.x); bb[ks][1] = (short)f2b(v0.y);
            bb[ks][2] = (short)f2b(v0.z); bb[ks][3] = (short)f2b(v0.w);
            bb[ks][4] = (short)f2b(v1.x); bb[ks][5] = (short)f2b(v1.y);
            bb[ks][6] = (short)f2b(v1.z); bb[ks][7] = (short)f2b(v1.w);
        }

        f32x4 acc[8];
#pragma unroll
        for (int n = 0; n < 8; ++n) acc[n] = (f32x4){0.f, 0.f, 0.f, 0.f};
#pragma unroll
        for (int n = 0; n < 8; ++n)
#pragma unroll
            for (int ks = 0; ks < 4; ++ks)
                acc[n] = __builtin_amdgcn_mfma_f32_16x16x32_bf16(
                             wfrag[n * 4 + ks], bb[ks], acc[n], 0, 0, 0);

        unsigned short* ob = (unsigned short*)&zbuf[wave][p][0];
        const int sw = (t & 7) * 2;
#pragma unroll
        for (int n = 0; n < 8; ++n) {
            ushort4 h;
            h.x = f2b(acc[n][0] + b1v[n].x);
            h.y = f2b(acc[n][1] + b1v[n].y);
            h.z = f2b(acc[n][2] + b1v[n].z);
            h.w = f2b(acc[n][3] + b1v[n].w);
            *(ushort4*)&ob[t * 136 + (((n * 4 + q) ^ sw) * 4)] = h;
        }
        const int rr = lane >> 4;
#pragma unroll
        for (int it = 0; it < 4; ++it) {
            const int r = it * 4 + rr;
            const uint4 v = *(const uint4*)&ob[r * 136 + (((2 * t) ^ ((r & 7) * 2)) * 4)];
            *(uint4*)(A + (size_t)(m0 + r) * 128 + t * 8) = v;
        }
        asm volatile("" ::: "memory");

        p ^= 1;
        tile = ntile;
    }
#undef STAGE
}

__global__ __launch_bounds__(256, 7)
void edge_kernel(const unsigned short* __restrict__ Asrc,
                 const unsigned short* __restrict__ Adst,
                 const int* __restrict__ pos_src,
                 const int* __restrict__ pos_dst,
                 const int* __restrict__ neg_src,
                 const int* __restrict__ neg_dst,
                 const float* __restrict__ W2,
                 const float* __restrict__ b2,
                 float* __restrict__ out)
{
    const int tid = threadIdx.x;
    const int t = tid & 15;
    const int g = tid >> 4;

    const bool is_pos = blockIdx.x < 8192;
    const int* __restrict__ sp = is_pos ? pos_src : neg_src;
    const int* __restrict__ dp = is_pos ? pos_dst : neg_dst;
    const int eb = (is_pos ? (int)blockIdx.x : (int)blockIdx.x - 8192) * 64;

    float w2r[8];
#pragma unroll
    for (int j = 0; j < 8; ++j) w2r[j] = W2[t * 8 + j];
    const float bias2 = b2[0];

    unsigned soff[4], doff[4];
#pragma unroll
    for (int i = 0; i < 4; ++i) {
        soff[i] = ((unsigned)sp[eb + i * 16 + g] << 8) + t * 16;
        doff[i] = ((unsigned)dp[eb + i * 16 + g] << 8) + t * 16;
    }

    const unsigned char* As = (const unsigned char*)Asrc;
    const unsigned char* Ad = (const unsigned char*)Adst;

    uint4 ua[4], ub[4];
#pragma unroll
    for (int i = 0; i < 4; ++i) {
        ua[i] = *(const uint4*)(As + soff[i]);
        ub[i] = *(const uint4*)(Ad + doff[i]);
    }
    asm volatile("" ::: "memory");

#define CHUNK(i, vm)                                                          \
    do {                                                                      \
        __builtin_amdgcn_s_waitcnt(0xF70 | (vm));                             \
        asm volatile("" ::: "memory");                                        \
        const unsigned* pa = (const unsigned*)&ua[i];                         \
        const unsigned* pb = (const unsigned*)&ub[i];                         \
        float acc = 0.f;                                                      \
        _Pragma("unroll")                                                     \
        for (int j2 = 0; j2 < 4; ++j2) {                                      \
            float h0 = b2f(pa[j2] & 0xFFFFu) + b2f(pb[j2] & 0xFFFFu);         \
            float h1 = b2f(pa[j2] >> 16)     + b2f(pb[j2] >> 16);             \
            h0 = fmaxf(h0, 0.f);                                              \
            h1 = fmaxf(h1, 0.f);                                              \
            acc = fmaf(h0, w2r[2 * j2], acc);                                 \
            acc = fmaf(h1, w2r[2 * j2 + 1], acc);                             \
        }                                                                     \
        acc += __shfl_xor(acc, 1);                                            \
        acc += __shfl_xor(acc, 2);                                            \
        acc += __shfl_xor(acc, 4);                                            \
        acc += __shfl_xor(acc, 8);                                            \
        if (t == 0) out[blockIdx.x * 64 + (i) * 16 + g] = acc + bias2;        \
    } while (0)

    CHUNK(0, 6);
    CHUNK(1, 4);
    CHUNK(2, 2);
    CHUNK(3, 0);
#undef CHUNK
}

extern "C" void kernel_launch(void* const* d_in, const int* in_sizes, int n_in,
                              void* d_out, int out_size, void* d_ws, size_t ws_size,
                              hipStream_t stream) {
    const float* z_src  = (const float*)d_in[0];
    const float* z_dst  = (const float*)d_in[1];
    const int* pos_src  = (const int*)d_in[2];
    const int* pos_dst  = (const int*)d_in[3];
    const int* neg_src  = (const int*)d_in[4];
    const int* neg_dst  = (const int*)d_in[5];
    const float* W1     = (const float*)d_in[6];
    const float* b1     = (const float*)d_in[7];
    const float* W2     = (const float*)d_in[8];
    const float* b2     = (const float*)d_in[9];
    float* out = (float*)d_out;

    unsigned short* Asrc = (unsigned short*)d_ws;                 // 25.6 MB
    unsigned short* Adst = Asrc + (size_t)N_NODES * HIDDEN;       // 25.6 MB
    unsigned short* Wp   = Adst + (size_t)N_NODES * HIDDEN;       // 64 KB (fallback only)

    void* args[13] = {
        (void*)&z_src, (void*)&z_dst,
        (void*)&pos_src, (void*)&pos_dst, (void*)&neg_src, (void*)&neg_dst,
        (void*)&W1, (void*)&b1, (void*)&W2, (void*)&b2,
        (void*)&Asrc, (void*)&Adst, (void*)&out
    };
    hipError_t e = hipLaunchCooperativeKernel((const void*)fused_kernel,
                                              dim3(512), dim3(256),
                                              args, 0u, stream);
    if (e != hipSuccess) {
        // fallback: R2's verified 3-kernel pipeline
        wp_kernel<<<dim3(32, 2), 64, 0, stream>>>(W1, Wp);
        precompute_kernel<<<dim3(PBLK, 2), 256, 0, stream>>>(z_src, z_dst, Wp,
                                                             b1, Asrc, Adst);
        edge_kernel<<<16384, 256, 0, stream>>>(Asrc, Adst, pos_src, pos_dst,
                                               neg_src, neg_dst, W2, b2, out);
    }
}

// Round 4
// 217.216 us; speedup vs baseline: 1.9172x; 1.9172x over previous
//
#include <hip/hip_runtime.h>
#include <hip/hip_bf16.h>
#include <cstdint>

#define N_NODES 100000
#define HIDDEN  128
#define NEDGE   524288     // E; 2E = 16384 blocks x 64 edges
#define NT      6250       // 16-row wave-tiles per table (100000 = 16*6250)
#define PBLK    256        // precompute grid.x
#define WSTRIDE (PBLK * 4) // wave-tile stride (4 waves/block)

typedef __attribute__((ext_vector_type(8))) short short8;
typedef __attribute__((ext_vector_type(4))) float f32x4;
typedef __attribute__((ext_vector_type(4))) unsigned int u32x4;

__device__ __forceinline__ unsigned short f2b(float f) {
    unsigned u = __float_as_uint(f);
    u += 0x7FFFu + ((u >> 16) & 1u);   // RNE; inputs finite
    return (unsigned short)(u >> 16);
}
__device__ __forceinline__ float b2f(unsigned x16) {
    return __uint_as_float(x16 << 16);
}

// async 16B/lane global->LDS. lds dest wave-uniform; HW adds lane*16.
__device__ __forceinline__ void async_copy16(const float* g, float* l) {
    __builtin_amdgcn_global_load_lds(
        (const __attribute__((address_space(1))) unsigned int*)g,
        (__attribute__((address_space(3))) unsigned int*)l,
        16, 0, 0);
}

// Pack W1 halves into MFMA A-fragment order (bf16):
// Wp[tb][f=n*4+ks][lane][8] = W1[tb*128 + ks*32 + q*8 + j][n*16 + t], lane=q*16+t
__global__ void wp_kernel(const float* __restrict__ W1,
                          unsigned short* __restrict__ Wp)
{
    const int f = blockIdx.x;        // 0..31
    const int tb = blockIdx.y;       // 0..1
    const int lane = threadIdx.x;    // 0..63
    const int t = lane & 15, q = lane >> 4;
    const int n = f >> 2, ks = f & 3;
    short8 v;
#pragma unroll
    for (int j = 0; j < 8; ++j)
        v[j] = (short)f2b(W1[(size_t)(tb * 128 + ks * 32 + q * 8 + j) * 128 + n * 16 + t]);
    *(short8*)(Wp + ((size_t)(tb * 32 + f) * 64 + lane) * 8) = v;
}

// A[m][n] = sum_k z[m][k] * W1half[k][n] (+ b1[n] for table 0), bf16 out.
// (R2-verified structure, unchanged — model puts it ~at the HBM roofline
// for its 153.6 MB of traffic.)
__global__ __launch_bounds__(256, 2)
void precompute_kernel(const float* __restrict__ z_src,
                       const float* __restrict__ z_dst,
                       const unsigned short* __restrict__ Wp,
                       const float* __restrict__ b1,
                       unsigned short* __restrict__ Asrc,
                       unsigned short* __restrict__ Adst)
{
    const int table = blockIdx.y;
    const float* __restrict__ z = table ? z_dst : z_src;
    unsigned short* __restrict__ A = table ? Adst : Asrc;

    __shared__ float zbuf[4][2][2048];   // 64 KB: per-wave double buffer

    const int tid = threadIdx.x;
    const int wave = tid >> 6;
    const int lane = tid & 63;
    const int t = lane & 15;
    const int q = lane >> 4;

    short8 wfrag[32];
    {
        const unsigned short* wp = Wp + ((size_t)table * 32 * 64 + lane) * 8;
#pragma unroll
        for (int f = 0; f < 32; ++f)
            wfrag[f] = *(const short8*)(wp + (size_t)f * 64 * 8);
    }

    float4 b1v[8];
#pragma unroll
    for (int n = 0; n < 8; ++n)
        b1v[n] = (table == 0) ? *(const float4*)(b1 + n * 16 + q * 4)
                              : make_float4(0.f, 0.f, 0.f, 0.f);

    const int lhi = lane >> 5;       // 0/1
    const int llo = lane & 31;
#define STAGE(m0, p)                                                          \
    do {                                                                      \
        _Pragma("unroll")                                                     \
        for (int j = 0; j < 8; ++j) {                                         \
            const int r = j * 2 + lhi;                                        \
            const int c = llo ^ (r & 7);                                      \
            async_copy16(z + (size_t)((m0) + r) * 128 + c * 4,                \
                         &zbuf[wave][p][j * 256]);                            \
        }                                                                     \
    } while (0)

    int tile = blockIdx.x * 4 + wave;   // < 1024 < NT always
    int p = 0;
    STAGE(tile * 16, 0);
    __builtin_amdgcn_s_waitcnt(0xF70);  // vmcnt(0)
    asm volatile("" ::: "memory");

    while (tile < NT) {
        const int m0 = tile * 16;
        const int ntile = tile + WSTRIDE;
        const int nm0 = (ntile < NT ? ntile : tile) * 16;  // clamp: dummy reload
        STAGE(nm0, p ^ 1);                  // issue next tile's 8 loads first
        asm volatile("" ::: "memory");
        __builtin_amdgcn_s_waitcnt(0xF78);  // vmcnt(8)
        asm volatile("" ::: "memory");

        short8 bb[4];
#pragma unroll
        for (int ks = 0; ks < 4; ++ks) {
            const int c0 = ks * 8 + 2 * q;
            const int s = t & 7;
            const float4 v0 = *(const float4*)&zbuf[wave][p][(t * 32 + (c0 ^ s)) * 4];
            const float4 v1 = *(const float4*)&zbuf[wave][p][(t * 32 + ((c0 + 1) ^ s)) * 4];
            bb[ks][0] = (short)f2b(v0.x); bb[ks][1] = (short)f2b(v0.y);
            bb[ks][2] = (short)f2b(v0.z); bb[ks][3] = (short)f2b(v0.w);
            bb[ks][4] = (short)f2b(v1.x); bb[ks][5] = (short)f2b(v1.y);
            bb[ks][6] = (short)f2b(v1.z); bb[ks][7] = (short)f2b(v1.w);
        }

        f32x4 acc[8];
#pragma unroll
        for (int n = 0; n < 8; ++n) acc[n] = (f32x4){0.f, 0.f, 0.f, 0.f};
#pragma unroll
        for (int n = 0; n < 8; ++n)
#pragma unroll
            for (int ks = 0; ks < 4; ++ks)
                acc[n] = __builtin_amdgcn_mfma_f32_16x16x32_bf16(
                             wfrag[n * 4 + ks], bb[ks], acc[n], 0, 0, 0);

        unsigned short* ob = (unsigned short*)&zbuf[wave][p][0];
        const int sw = (t & 7) * 2;
#pragma unroll
        for (int n = 0; n < 8; ++n) {
            ushort4 h;
            h.x = f2b(acc[n][0] + b1v[n].x);
            h.y = f2b(acc[n][1] + b1v[n].y);
            h.z = f2b(acc[n][2] + b1v[n].z);
            h.w = f2b(acc[n][3] + b1v[n].w);
            *(ushort4*)&ob[t * 136 + (((n * 4 + q) ^ sw) * 4)] = h;
        }
        const int rr = lane >> 4;            // 0..3
#pragma unroll
        for (int it = 0; it < 4; ++it) {
            const int r = it * 4 + rr;
            const uint4 v = *(const uint4*)&ob[r * 136 + (((2 * t) ^ ((r & 7) * 2)) * 4)];
            *(uint4*)(A + (size_t)(m0 + r) * 128 + t * 8) = v;
        }
        asm volatile("" ::: "memory");

        p ^= 1;
        tile = ntile;
    }
#undef STAGE
}

// 16 lanes per edge; lane owns 8 hidden units (16B bf16 gather per table).
// out[e] = sum_j relu(Asrc'[s][j] + Adst[d][j]) * W2[j] + b2   (b1 folded in)
//
// R4: asm-forced 8-deep gather pipeline. R0/R2 both compiled to VGPR 28-32
// (compiler squashed the C-level pipeline to ~2 loads in flight) and both
// measured 73-75 us; R3's fused phase-2 at 8 waves/CU ran ~3x slower =>
// latency-bound, not fabric-BW-bound. Here the 8 gathers are inline-asm
// global_load_dwordx4 (issue order pinned; defs are live VGPR quads) and
// each drain is an asm s_waitcnt vmcnt(N) with the consumed quads tied as
// "+v" operands, so uses data-depend on the waitcnt (anti-hoist, rule #18)
// + sched_barrier(0). Stores deferred to the tail so vmcnt counts see only
// loads. ~65 VGPR @ launch_bounds(256,6) -> 24 waves/CU, 8KB/wave in flight.
__global__ __launch_bounds__(256, 6)
void edge_kernel(const unsigned short* __restrict__ Asrc,
                 const unsigned short* __restrict__ Adst,
                 const int* __restrict__ pos_src,
                 const int* __restrict__ pos_dst,
                 const int* __restrict__ neg_src,
                 const int* __restrict__ neg_dst,
                 const float* __restrict__ W2,
                 const float* __restrict__ b2,
                 float* __restrict__ out)
{
    const int tid = threadIdx.x;
    const int t = tid & 15;      // hidden slice t*8 .. t*8+7
    const int g = tid >> 4;      // edge group within block (0..15)

    const bool is_pos = blockIdx.x < 8192;
    const int* __restrict__ sp = is_pos ? pos_src : neg_src;
    const int* __restrict__ dp = is_pos ? pos_dst : neg_dst;
    const int eb = (is_pos ? (int)blockIdx.x : (int)blockIdx.x - 8192) * 64;

    float w2r[8];
#pragma unroll
    for (int j = 0; j < 8; ++j) w2r[j] = W2[t * 8 + j];
    const float bias2 = b2[0];

    // byte offsets into the two tables (row = idx*256B, lane slice t*16B)
    unsigned soff[4], doff[4];
#pragma unroll
    for (int i = 0; i < 4; ++i) {
        soff[i] = ((unsigned)sp[eb + i * 16 + g] << 8) + t * 16;
        doff[i] = ((unsigned)dp[eb + i * 16 + g] << 8) + t * 16;
    }

    // ---- issue all 8 gathers via asm: order pinned, defs live ----
    u32x4 ua[4], ub[4];
#pragma unroll
    for (int i = 0; i < 4; ++i) {
        asm volatile("global_load_dwordx4 %0, %1, %2"
                     : "=v"(ua[i]) : "v"(soff[i]), "s"(Asrc));
        asm volatile("global_load_dwordx4 %0, %1, %2"
                     : "=v"(ub[i]) : "v"(doff[i]), "s"(Adst));
    }

    float res[4];

    // drain: chunk i needs loads 2i,2i+1 retired -> vmcnt(6-2i).
    // "+v" ties: chunk-i compute data-depends on its waitcnt.
#define CHUNK(i, VMSTR)                                                       \
    do {                                                                      \
        asm volatile("s_waitcnt " VMSTR : "+v"(ua[i]), "+v"(ub[i]));          \
        __builtin_amdgcn_sched_barrier(0);                                    \
        const unsigned* pa = (const unsigned*)&ua[i];                         \
        const unsigned* pb = (const unsigned*)&ub[i];                         \
        float acc = 0.f;                                                      \
        _Pragma("unroll")                                                     \
        for (int j2 = 0; j2 < 4; ++j2) {                                      \
            float h0 = b2f(pa[j2] & 0xFFFFu) + b2f(pb[j2] & 0xFFFFu);         \
            float h1 = b2f(pa[j2] >> 16)     + b2f(pb[j2] >> 16);             \
            h0 = fmaxf(h0, 0.f);                                              \
            h1 = fmaxf(h1, 0.f);                                              \
            acc = fmaf(h0, w2r[2 * j2], acc);                                 \
            acc = fmaf(h1, w2r[2 * j2 + 1], acc);                             \
        }                                                                     \
        acc += __shfl_xor(acc, 1);                                            \
        acc += __shfl_xor(acc, 2);                                            \
        acc += __shfl_xor(acc, 4);                                            \
        acc += __shfl_xor(acc, 8);                                            \
        res[i] = acc + bias2;                                                 \
    } while (0)

    CHUNK(0, "vmcnt(6)");
    CHUNK(1, "vmcnt(4)");
    CHUNK(2, "vmcnt(2)");
    CHUNK(3, "vmcnt(0)");
#undef CHUNK

    // tail: stores only after all drains (keeps vmcnt counts load-only)
    if (t == 0) {
#pragma unroll
        for (int i = 0; i < 4; ++i)
            out[blockIdx.x * 64 + i * 16 + g] = res[i];
    }
}

extern "C" void kernel_launch(void* const* d_in, const int* in_sizes, int n_in,
                              void* d_out, int out_size, void* d_ws, size_t ws_size,
                              hipStream_t stream) {
    const float* z_src  = (const float*)d_in[0];
    const float* z_dst  = (const float*)d_in[1];
    const int* pos_src  = (const int*)d_in[2];
    const int* pos_dst  = (const int*)d_in[3];
    const int* neg_src  = (const int*)d_in[4];
    const int* neg_dst  = (const int*)d_in[5];
    const float* W1     = (const float*)d_in[6];
    const float* b1     = (const float*)d_in[7];
    const float* W2     = (const float*)d_in[8];
    const float* b2     = (const float*)d_in[9];
    float* out = (float*)d_out;

    unsigned short* Asrc = (unsigned short*)d_ws;                 // 25.6 MB
    unsigned short* Adst = Asrc + (size_t)N_NODES * HIDDEN;       // 25.6 MB
    unsigned short* Wp   = Adst + (size_t)N_NODES * HIDDEN;       // 64 KB

    wp_kernel<<<dim3(32, 2), 64, 0, stream>>>(W1, Wp);

    precompute_kernel<<<dim3(PBLK, 2), 256, 0, stream>>>(z_src, z_dst, Wp, b1,
                                                         Asrc, Adst);

    edge_kernel<<<16384, 256, 0, stream>>>(Asrc, Adst, pos_src, pos_dst,
                                           neg_src, neg_dst, W2, b2, out);
}